// Round 10
// baseline (425.584 us; speedup 1.0000x reference)
//
#include <hip/hip_runtime.h>
#include <hip/hip_bf16.h>
#include <string.h>

using short8 = __attribute__((ext_vector_type(8))) short;
using f32x4  = __attribute__((ext_vector_type(4))) float;

#define POOLN     9216       // 144*64 elements (bf16) per image
#define FC1N      128
#define WT2_ELEMS 18432      // 36*64*8
#define WT2_BYTES 36864
#define H1S_STRIDE 36        // shorts per position row (72 B)
#define P_IMGS    8          // images pipelined per block

#define GLL16(gp, lp) __builtin_amdgcn_global_load_lds( \
    (const __attribute__((address_space(1))) void*)(gp), \
    (__attribute__((address_space(3))) void*)(lp), 16, 0, 0)

static __device__ __forceinline__ unsigned short f2bf(float f) {
  unsigned int u = __builtin_bit_cast(unsigned int, f);
  unsigned int r = (u + 0x7FFFu + ((u >> 16) & 1u)) >> 16;
  return (unsigned short)r;
}

// packed RNE pair convert -> v_cvt_pk_bf16_f32
static __device__ __forceinline__ unsigned int pkbf(float lo, float hi) {
  __hip_bfloat162 h2 = __float22bfloat162_rn(make_float2(lo, hi));
  unsigned int r;
  memcpy(&r, &h2, sizeof(r));
  return r;
}

// ---- one-off: w2 fp32 [64][32][9] -> wt2 bf16 fragment order [(tap*4+n)][lane][8]
__global__ __launch_bounds__(256) void k_wt2(const float* __restrict__ w2,
    unsigned short* __restrict__ wt2) {
  int idx = blockIdx.x * 256 + threadIdx.x;
  if (idx >= WT2_ELEMS) return;
  int j = idx & 7;
  int l = (idx >> 3) & 63;
  int tn = idx >> 9;            // 0..35
  int tap = tn >> 2, n = tn & 3;
  int oc = n * 16 + (l & 15);
  int ic = (l >> 4) * 8 + j;
  wt2[idx] = f2bf(w2[oc * 288 + ic * 9 + tap]);
}

// ---- one-off: fc1_w [128][9216 (oc*144+sp)] -> fw1t bf16 [128][9216 (sp*64+oc)] ----
__global__ __launch_bounds__(256) void k_fw1t(const float* __restrict__ w,
    unsigned short* __restrict__ wt) {
  int c = blockIdx.x;
  __shared__ float row[9216];
  int t = threadIdx.x;
  const float* src = w + (size_t)c * 9216;
  for (int i = t; i < 9216; i += 256) row[i] = src[i];
  __syncthreads();
  unsigned short* dst = wt + (size_t)c * 9216;
  for (int k = t; k < 9216; k += 256) {
    int sp = k >> 6, oc = k & 63;
    dst[k] = f2bf(row[oc * 144 + sp]);
  }
}

// ---- pipelined fused conv1+conv2+pool: 8 images/block, wave-specialized ----
// waves 0-3: conv1(img p) -> h1s[p&1] (VALU pipe; x read from global)
// waves 4-7: conv2(img p-1) <- h1s[(p&1)^1] (LDS + MFMA pipes)
// One barrier per phase; pipes overlap across the wave split (m114).
__global__ __launch_bounds__(512, 2) void kc_pipe(const float* __restrict__ x,
    const float* __restrict__ w1, const float* __restrict__ b1,
    const unsigned short* __restrict__ wt2, const float* __restrict__ b2,
    unsigned short* __restrict__ pooled, int nr) {
  __shared__ __align__(16) unsigned short h1s[2][676 * H1S_STRIDE];  // 97344 B
  int t = threadIdx.x;
  int w = t >> 6, ln = t & 63;
  int ibase = blockIdx.x * P_IMGS;
  int navail = nr - ibase;
  int n = navail < P_IMGS ? navail : P_IMGS;   // block-uniform

  // conv1 lane geometry (waves 0-3): lane -> column, slide 13 rows
  int half = (ln >= 26);
  int xcol = ln - half * 26;
  int y0 = half * 13;

  // conv2 lane geometry (waves 4-7)
  int col = ln & 15;
  int g = (ln >> 4) & 3;
  int wq = w - 4;

  for (int p = 0; p <= n; ++p) {
    asm volatile("" ::: "memory");   // defeat LICM: keep per-phase reloads in-branch
    int cb = p & 1;
    if (w < 4) {
      if (p < n && ln < 52) {
        // reload weights each phase (keeps them out of the conv2 live-range)
        float wr[8][9], br[8];
        #pragma unroll
        for (int o = 0; o < 8; ++o) {
          br[o] = b1[w * 8 + o];
          #pragma unroll
          for (int q = 0; q < 9; ++q) wr[o][q] = w1[(w * 8 + o) * 9 + q];
        }
        const float* xg = x + (size_t)(ibase + p) * 784;
        float win[3][3];
        #pragma unroll
        for (int c = 0; c < 3; ++c) {
          win[1][c] = xg[y0 * 28 + xcol + c];
          win[2][c] = xg[(y0 + 1) * 28 + xcol + c];
        }
        #pragma unroll
        for (int i = 0; i < 13; ++i) {
          #pragma unroll
          for (int c = 0; c < 3; ++c) {
            win[0][c] = win[1][c];
            win[1][c] = win[2][c];
            win[2][c] = xg[(y0 + i + 2) * 28 + xcol + c];
          }
          unsigned int packed[4];
          #pragma unroll
          for (int o = 0; o < 8; o += 2) {
            float s0 = br[o], s1 = br[o + 1];
            #pragma unroll
            for (int r = 0; r < 3; ++r)
              #pragma unroll
              for (int c = 0; c < 3; ++c) {
                s0 = fmaf(win[r][c], wr[o][r * 3 + c], s0);
                s1 = fmaf(win[r][c], wr[o + 1][r * 3 + c], s1);
              }
            packed[o >> 1] = pkbf(fmaxf(s0, 0.f), fmaxf(s1, 0.f));
          }
          int pos = (y0 + i) * 26 + xcol;
          unsigned short* dst = &h1s[cb][pos * H1S_STRIDE + w * 8];
          *(uint2*)dst = make_uint2(packed[0], packed[1]);
          *(uint2*)(dst + 4) = make_uint2(packed[2], packed[3]);
        }
      }
    } else {
      if (p >= 1) {
        const char* hsb = (const char*)h1s[cb ^ 1];
        int abase[9];
        #pragma unroll
        for (int m = 0; m < 9; ++m) {
          int mt = wq * 9 + m;
          int pr = mt / 3, tc = mt - pr * 3;
          int y = 2 * pr + (col & 1);
          int xx = 8 * tc + (col >> 1);
          abase[m] = (y * 26 + xx) * (H1S_STRIDE * 2) + g * 16;
        }
        f32x4 acc[9][4];
        #pragma unroll
        for (int m = 0; m < 9; ++m)
          #pragma unroll
          for (int nn = 0; nn < 4; ++nn)
            acc[m][nn] = (f32x4){0.f, 0.f, 0.f, 0.f};

        #pragma unroll
        for (int tap = 0; tap < 9; ++tap) {
          int ky = tap / 3, kx = tap - ky * 3;
          int toff = (ky * 26 + kx) * (H1S_STRIDE * 2);
          short8 bf[4];
          #pragma unroll
          for (int nn = 0; nn < 4; ++nn)
            bf[nn] = *(const short8*)(wt2 + ((size_t)(tap * 4 + nn) * 64 + ln) * 8);
          #pragma unroll
          for (int m = 0; m < 9; ++m) {
            union { short8 v; uint2 d[2]; } af;
            af.d[0] = *(const uint2*)(hsb + abase[m] + toff);
            af.d[1] = *(const uint2*)(hsb + abase[m] + toff + 8);
            #pragma unroll
            for (int nn = 0; nn < 4; ++nn)
              acc[m][nn] = __builtin_amdgcn_mfma_f32_16x16x32_bf16(af.v, bf[nn], acc[m][nn], 0, 0, 0);
          }
        }

        float bias[4];
        #pragma unroll
        for (int nn = 0; nn < 4; ++nn) bias[nn] = b2[nn * 16 + col];
        unsigned short* pp = pooled + (size_t)(ibase + p - 1) * POOLN;
        #pragma unroll
        for (int m = 0; m < 9; ++m) {
          int mt = wq * 9 + m;
          int pr = mt / 3, tc = mt - pr * 3;
          int sp = pr * 12 + tc * 4 + g;
          float rv[4];
          #pragma unroll
          for (int nn = 0; nn < 4; ++nn) {
            f32x4 a = acc[m][nn];
            float v = fmaxf(fmaxf(a[0], a[1]), fmaxf(a[2], a[3]));
            rv[nn] = fmaxf(v + bias[nn], 0.f);
          }
          unsigned int p01 = pkbf(rv[0], rv[1]);
          unsigned int p23 = pkbf(rv[2], rv[3]);
          unsigned short* pr0 = pp + sp * 64 + col;
          pr0[0]  = (unsigned short)p01;
          pr0[16] = (unsigned short)(p01 >> 16);
          pr0[32] = (unsigned short)p23;
          pr0[48] = (unsigned short)(p23 >> 16);
        }
      }
    }
    __syncthreads();
  }
}

// ---- fc1 via MFMA, split-K=4: pooled bf16 [nr][9216] @ fw1t bf16 [128][9216]^T
__global__ __launch_bounds__(256) void k3_fc1_mfma(
    const unsigned short* __restrict__ a, const unsigned short* __restrict__ w,
    float* __restrict__ part, int nrpad) {
  __shared__ __align__(16) unsigned short As[2][4096];   // [64][64] bf16 x2
  __shared__ __align__(16) unsigned short Bs[2][8192];   // [128][64] bf16 x2
  int row0 = blockIdx.x * 64;
  int kbase = blockIdx.y * 2304;
  int t = threadIdx.x;
  int wv = t >> 6, l = t & 63;
  int rsub = l >> 3;
  int src_sw = ((l & 7) ^ rsub) << 4;

  const char* abase = (const char*)a + (size_t)row0 * 18432;
  const char* bbase = (const char*)w;

  auto stage = [&](int buf, int step) {
    size_t k0b = (size_t)(kbase + step * 64) * 2;
    #pragma unroll
    for (int i = 0; i < 2; ++i) {
      int c = wv * 2 + i;
      GLL16(abase + (size_t)(c * 8 + rsub) * 18432 + k0b + src_sw,
            (char*)As[buf] + c * 1024);
    }
    #pragma unroll
    for (int i = 0; i < 4; ++i) {
      int c = wv * 4 + i;
      GLL16(bbase + (size_t)(c * 8 + rsub) * 18432 + k0b + src_sw,
            (char*)Bs[buf] + c * 1024);
    }
  };

  int wm = wv >> 1, wn = wv & 1;
  int lr = l & 15, g2 = l >> 4;
  int rdxor = (lr & 7) << 4;

  f32x4 acc[2][4];
  #pragma unroll
  for (int mf = 0; mf < 2; ++mf)
    #pragma unroll
    for (int nf = 0; nf < 4; ++nf)
      acc[mf][nf] = (f32x4){0.f, 0.f, 0.f, 0.f};

  stage(0, 0);
  __syncthreads();
  for (int s = 0; s < 36; ++s) {
    int cur = s & 1;
    if (s < 35) stage(cur ^ 1, s + 1);
    const char* Ab = (const char*)As[cur];
    const char* Bb = (const char*)Bs[cur];
    #pragma unroll
    for (int ksub = 0; ksub < 2; ++ksub) {
      int koff = (ksub * 64 + g2 * 16) ^ rdxor;
      short8 af0 = *(const short8*)(Ab + (wm * 32 + lr) * 128 + koff);
      short8 af1 = *(const short8*)(Ab + (wm * 32 + 16 + lr) * 128 + koff);
      short8 bf[4];
      #pragma unroll
      for (int nf = 0; nf < 4; ++nf)
        bf[nf] = *(const short8*)(Bb + (wn * 64 + nf * 16 + lr) * 128 + koff);
      #pragma unroll
      for (int nf = 0; nf < 4; ++nf) {
        acc[0][nf] = __builtin_amdgcn_mfma_f32_16x16x32_bf16(af0, bf[nf], acc[0][nf], 0, 0, 0);
        acc[1][nf] = __builtin_amdgcn_mfma_f32_16x16x32_bf16(af1, bf[nf], acc[1][nf], 0, 0, 0);
      }
    }
    __syncthreads();
  }

  float* pp = part + (size_t)blockIdx.y * nrpad * 128 + (size_t)row0 * 128;
  #pragma unroll
  for (int mf = 0; mf < 2; ++mf)
    #pragma unroll
    for (int nf = 0; nf < 4; ++nf)
      #pragma unroll
      for (int rr = 0; rr < 4; ++rr) {
        int r = wm * 32 + mf * 16 + g2 * 4 + rr;
        int c = wn * 64 + nf * 16 + lr;
        pp[r * 128 + c] = acc[mf][nf][rr];
      }
}

// ---- reduce 4 split-K partials + bias + relu -> f1o fp32 [nr][128] ----
__global__ __launch_bounds__(256) void k_red(const float* __restrict__ part,
    const float* __restrict__ bias, float* __restrict__ f1o, int nr, int nrpad) {
  int i = blockIdx.x * 256 + threadIdx.x;
  if (i >= nr * 128) return;
  size_t stride = (size_t)nrpad * 128;
  float s = part[i] + part[stride + i] + part[2 * stride + i] + part[3 * stride + i];
  f1o[i] = fmaxf(s + bias[i & 127], 0.f);
}

// ---- fc2 ----
__global__ __launch_bounds__(256) void k4_fc2(const float* __restrict__ h,
    const float* __restrict__ w, const float* __restrict__ bias,
    float* __restrict__ out, int nr) {
  int idx = blockIdx.x * 256 + threadIdx.x;
  if (idx >= nr * 10) return;
  int b = idx / 10;
  int j = idx - b * 10;
  const float4* hp = (const float4*)(h + (size_t)b * 128);
  const float4* wp = (const float4*)(w + (size_t)j * 128);
  float s = 0.f;
  #pragma unroll
  for (int q = 0; q < 32; ++q) {
    float4 hv = hp[q];
    float4 wv = wp[q];
    s = fmaf(hv.x, wv.x, s);
    s = fmaf(hv.y, wv.y, s);
    s = fmaf(hv.z, wv.z, s);
    s = fmaf(hv.w, wv.w, s);
  }
  out[idx] = s + bias[j];
}

extern "C" void kernel_launch(void* const* d_in, const int* in_sizes, int n_in,
                              void* d_out, int out_size, void* d_ws, size_t ws_size,
                              hipStream_t stream) {
  const float* x   = (const float*)d_in[0];
  const float* w1  = (const float*)d_in[1];
  const float* b1  = (const float*)d_in[2];
  const float* w2  = (const float*)d_in[3];
  const float* b2  = (const float*)d_in[4];
  const float* fw1 = (const float*)d_in[5];
  const float* fb1 = (const float*)d_in[6];
  const float* fw2 = (const float*)d_in[7];
  const float* fb2 = (const float*)d_in[8];
  float* out = (float*)d_out;

  const int B = in_sizes[0] / 784;

  unsigned short* wt2 = (unsigned short*)d_ws;                        // 36864 B
  unsigned short* fw1t = (unsigned short*)((char*)d_ws + WT2_BYTES);  // 2359296 B
  const size_t carve = WT2_BYTES + (size_t)9216 * 128 * 2;
  char* base = (char*)d_ws + carve;
  size_t avail = (ws_size > carve) ? ws_size - carve : 0;
  const size_t per_img = (size_t)POOLN * 2 + 512 + 2048;
  int Bc = (int)(avail / per_img);
  if (Bc > B) Bc = B;
  Bc &= ~63;
  if (Bc < 64) Bc = 64;

  unsigned short* pooled = (unsigned short*)base;
  float* f1o = (float*)(base + (size_t)Bc * (POOLN * 2));
  float* part = (float*)(base + (size_t)Bc * (POOLN * 2 + 512));

  k_wt2<<<(WT2_ELEMS + 255) / 256, 256, 0, stream>>>(w2, wt2);
  k_fw1t<<<128, 256, 0, stream>>>(fw1, fw1t);

  for (int i0 = 0; i0 < B; i0 += Bc) {
    int nr = (B - i0 < Bc) ? (B - i0) : Bc;
    int mtiles = (nr + 63) / 64;
    int nrpad = mtiles * 64;
    int nblk = (nr + P_IMGS - 1) / P_IMGS;
    kc_pipe<<<nblk, 512, 0, stream>>>(x + (size_t)i0 * 784, w1, b1, wt2, b2,
                                      pooled, nr);
    k3_fc1_mfma<<<dim3(mtiles, 4), 256, 0, stream>>>(pooled, fw1t, part, nrpad);
    k_red<<<(nr * 128 + 255) / 256, 256, 0, stream>>>(part, fb1, f1o, nr, nrpad);
    k4_fc2<<<(nr * 10 + 255) / 256, 256, 0, stream>>>(f1o, fw2, fb2,
                                                      out + (size_t)i0 * 10, nr);
  }
}

// Round 11
// 157.858 us; speedup vs baseline: 2.6960x; 2.6960x over previous
//
#include <hip/hip_runtime.h>
#include <hip/hip_bf16.h>
#include <string.h>

using short8 = __attribute__((ext_vector_type(8))) short;
using f32x4  = __attribute__((ext_vector_type(4))) float;

#define POOLN     9216       // 144*64 elements (bf16) per image
#define FC1N      128
#define WT2_ELEMS 18432      // 36*64*8
#define WT2_BYTES 36864
#define H1S_STRIDE 36        // shorts per position row (72 B)
#define XS_STRIDE  29        // floats per x row (odd -> conflict-free)

#define GLL16(gp, lp) __builtin_amdgcn_global_load_lds( \
    (const __attribute__((address_space(1))) void*)(gp), \
    (__attribute__((address_space(3))) void*)(lp), 16, 0, 0)

static __device__ __forceinline__ unsigned short f2bf(float f) {
  unsigned int u = __builtin_bit_cast(unsigned int, f);
  unsigned int r = (u + 0x7FFFu + ((u >> 16) & 1u)) >> 16;
  return (unsigned short)r;
}

// packed RNE pair convert -> v_cvt_pk_bf16_f32
static __device__ __forceinline__ unsigned int pkbf(float lo, float hi) {
  __hip_bfloat162 h2 = __float22bfloat162_rn(make_float2(lo, hi));
  unsigned int r;
  memcpy(&r, &h2, sizeof(r));
  return r;
}

// ---- one-off: w2 fp32 [64][32][9] -> wt2 bf16 fragment order [(tap*4+n)][lane][8]
__global__ __launch_bounds__(256) void k_wt2(const float* __restrict__ w2,
    unsigned short* __restrict__ wt2) {
  int idx = blockIdx.x * 256 + threadIdx.x;
  if (idx >= WT2_ELEMS) return;
  int j = idx & 7;
  int l = (idx >> 3) & 63;
  int tn = idx >> 9;            // 0..35
  int tap = tn >> 2, n = tn & 3;
  int oc = n * 16 + (l & 15);
  int ic = (l >> 4) * 8 + j;
  wt2[idx] = f2bf(w2[oc * 288 + ic * 9 + tap]);
}

// ---- one-off: fc1_w [128][9216 (oc*144+sp)] -> fw1t bf16 [128][9216 (sp*64+oc)] ----
__global__ __launch_bounds__(256) void k_fw1t(const float* __restrict__ w,
    unsigned short* __restrict__ wt) {
  int c = blockIdx.x;
  __shared__ float row[9216];
  int t = threadIdx.x;
  const float* src = w + (size_t)c * 9216;
  for (int i = t; i < 9216; i += 256) row[i] = src[i];
  __syncthreads();
  unsigned short* dst = wt + (size_t)c * 9216;
  for (int k = t; k < 9216; k += 256) {
    int sp = k >> 6, oc = k & 63;
    dst[k] = f2bf(row[oc * 144 + sp]);
  }
}

// ---- fused conv1+relu+conv2+relu+maxpool, row-third tiles ----
// grid (nr, 3): blockIdx.y = tt selects pooled rows 4tt..4tt+3.
// conv1: h1 local rows 0..9 (global 8tt..8tt+9), 8 ch/wave, lane=column.
// conv2: wave wv = local pooled row; 3 m-tiles (tc 0..2); acc[3][4] = 48 regs.
// LDS 19.6 KB -> 3 blocks/CU at launch_bounds(256,3) (reg cap ~170).
__global__ __launch_bounds__(256, 3) void kc_fused(const float* __restrict__ x,
    const float* __restrict__ w1, const float* __restrict__ b1,
    const unsigned short* __restrict__ wt2, const float* __restrict__ b2,
    unsigned short* __restrict__ pooled) {
  int img = blockIdx.x;
  int tt = blockIdx.y;
  __shared__ float xs[12 * XS_STRIDE];                            // 1392 B
  __shared__ __align__(16) unsigned short h1s[260 * H1S_STRIDE];  // 18720 B
  int t = threadIdx.x;
  int wv = t >> 6, ln = t & 63;
  int r0x = tt * 8;                      // first x/h1 global row of this third

  const float* xp = x + (size_t)img * 784 + (size_t)r0x * 28;
  for (int i = t; i < 12 * 28; i += 256) {
    int r = i / 28, c = i - r * 28;
    xs[r * XS_STRIDE + c] = xp[r * 28 + c];
  }

  // conv1 weights: 8 channels per wave, wave-uniform
  int wvu = __builtin_amdgcn_readfirstlane(wv);
  float wr[8][9], br[8];
  #pragma unroll
  for (int o = 0; o < 8; ++o) {
    br[o] = b1[wvu * 8 + o];
    #pragma unroll
    for (int q = 0; q < 9; ++q) wr[o][q] = w1[(wvu * 8 + o) * 9 + q];
  }
  __syncthreads();

  // conv1: lane -> column, 2 halves x 5 rows each (local h1 rows 0..9)
  if (ln < 52) {
    int half = (ln >= 26);
    int xcol = ln - half * 26;          // 0..25
    int y0 = half * 5;                  // local row base
    float win[3][3];
    #pragma unroll
    for (int c = 0; c < 3; ++c) {
      win[1][c] = xs[(y0 + 0) * XS_STRIDE + xcol + c];
      win[2][c] = xs[(y0 + 1) * XS_STRIDE + xcol + c];
    }
    #pragma unroll
    for (int i = 0; i < 5; ++i) {
      #pragma unroll
      for (int c = 0; c < 3; ++c) {
        win[0][c] = win[1][c];
        win[1][c] = win[2][c];
        win[2][c] = xs[(y0 + i + 2) * XS_STRIDE + xcol + c];
      }
      unsigned int packed[4];
      #pragma unroll
      for (int o = 0; o < 8; o += 2) {
        float s0 = br[o], s1 = br[o + 1];
        #pragma unroll
        for (int r = 0; r < 3; ++r)
          #pragma unroll
          for (int c = 0; c < 3; ++c) {
            s0 = fmaf(win[r][c], wr[o][r * 3 + c], s0);
            s1 = fmaf(win[r][c], wr[o + 1][r * 3 + c], s1);
          }
        packed[o >> 1] = pkbf(fmaxf(s0, 0.f), fmaxf(s1, 0.f));
      }
      int pos = (y0 + i) * 26 + xcol;
      unsigned short* dst = &h1s[pos * H1S_STRIDE + wv * 8];
      *(uint2*)dst = make_uint2(packed[0], packed[1]);
      *(uint2*)(dst + 4) = make_uint2(packed[2], packed[3]);
    }
  }
  __syncthreads();

  // ---- conv2 + pool: wave = local pooled row, 3 m-tiles (tc 0..2) ----
  int col = ln & 15;
  int g = (ln >> 4) & 3;

  int abase[3];
  #pragma unroll
  for (int i = 0; i < 3; ++i) {
    int y = 2 * wv + (col & 1);                    // local h1 row
    int xx = 8 * i + (col >> 1);
    abase[i] = (y * 26 + xx) * (H1S_STRIDE * 2) + g * 16;
  }

  f32x4 acc[3][4];
  #pragma unroll
  for (int m = 0; m < 3; ++m)
    #pragma unroll
    for (int n = 0; n < 4; ++n)
      acc[m][n] = (f32x4){0.f, 0.f, 0.f, 0.f};

  const char* hsb = (const char*)h1s;
  #pragma unroll
  for (int tap = 0; tap < 9; ++tap) {
    int ky = tap / 3, kx = tap - ky * 3;
    int toff = (ky * 26 + kx) * (H1S_STRIDE * 2);
    short8 bf[4];
    #pragma unroll
    for (int n = 0; n < 4; ++n)
      bf[n] = *(const short8*)(wt2 + ((size_t)(tap * 4 + n) * 64 + ln) * 8);
    #pragma unroll
    for (int m = 0; m < 3; ++m) {
      union { short8 v; uint2 d[2]; } af;
      af.d[0] = *(const uint2*)(hsb + abase[m] + toff);
      af.d[1] = *(const uint2*)(hsb + abase[m] + toff + 8);
      #pragma unroll
      for (int n = 0; n < 4; ++n)
        acc[m][n] = __builtin_amdgcn_mfma_f32_16x16x32_bf16(af.v, bf[n], acc[m][n], 0, 0, 0);
    }
  }

  float bias[4];
  #pragma unroll
  for (int n = 0; n < 4; ++n) bias[n] = b2[n * 16 + col];
  unsigned short* pp = pooled + (size_t)img * POOLN;
  int pr = tt * 4 + wv;                            // global pooled row
  #pragma unroll
  for (int m = 0; m < 3; ++m) {
    int sp = pr * 12 + m * 4 + g;
    float rv[4];
    #pragma unroll
    for (int n = 0; n < 4; ++n) {
      f32x4 a = acc[m][n];
      float v = fmaxf(fmaxf(a[0], a[1]), fmaxf(a[2], a[3]));
      rv[n] = fmaxf(v + bias[n], 0.f);
    }
    unsigned int p01 = pkbf(rv[0], rv[1]);
    unsigned int p23 = pkbf(rv[2], rv[3]);
    unsigned short* pr0 = pp + sp * 64 + col;
    pr0[0]  = (unsigned short)p01;
    pr0[16] = (unsigned short)(p01 >> 16);
    pr0[32] = (unsigned short)p23;
    pr0[48] = (unsigned short)(p23 >> 16);
  }
}

// ---- fc1 via MFMA, split-K=4: pooled bf16 [nr][9216] @ fw1t bf16 [128][9216]^T
__global__ __launch_bounds__(256) void k3_fc1_mfma(
    const unsigned short* __restrict__ a, const unsigned short* __restrict__ w,
    float* __restrict__ part, int nrpad) {
  __shared__ __align__(16) unsigned short As[2][4096];   // [64][64] bf16 x2
  __shared__ __align__(16) unsigned short Bs[2][8192];   // [128][64] bf16 x2
  int row0 = blockIdx.x * 64;
  int kbase = blockIdx.y * 2304;
  int t = threadIdx.x;
  int wv = t >> 6, l = t & 63;
  int rsub = l >> 3;
  int src_sw = ((l & 7) ^ rsub) << 4;

  const char* abase = (const char*)a + (size_t)row0 * 18432;
  const char* bbase = (const char*)w;

  auto stage = [&](int buf, int step) {
    size_t k0b = (size_t)(kbase + step * 64) * 2;
    #pragma unroll
    for (int i = 0; i < 2; ++i) {
      int c = wv * 2 + i;
      GLL16(abase + (size_t)(c * 8 + rsub) * 18432 + k0b + src_sw,
            (char*)As[buf] + c * 1024);
    }
    #pragma unroll
    for (int i = 0; i < 4; ++i) {
      int c = wv * 4 + i;
      GLL16(bbase + (size_t)(c * 8 + rsub) * 18432 + k0b + src_sw,
            (char*)Bs[buf] + c * 1024);
    }
  };

  int wm = wv >> 1, wn = wv & 1;
  int lr = l & 15, g2 = l >> 4;
  int rdxor = (lr & 7) << 4;

  f32x4 acc[2][4];
  #pragma unroll
  for (int mf = 0; mf < 2; ++mf)
    #pragma unroll
    for (int nf = 0; nf < 4; ++nf)
      acc[mf][nf] = (f32x4){0.f, 0.f, 0.f, 0.f};

  stage(0, 0);
  __syncthreads();
  for (int s = 0; s < 36; ++s) {
    int cur = s & 1;
    if (s < 35) stage(cur ^ 1, s + 1);
    const char* Ab = (const char*)As[cur];
    const char* Bb = (const char*)Bs[cur];
    #pragma unroll
    for (int ksub = 0; ksub < 2; ++ksub) {
      int koff = (ksub * 64 + g2 * 16) ^ rdxor;
      short8 af0 = *(const short8*)(Ab + (wm * 32 + lr) * 128 + koff);
      short8 af1 = *(const short8*)(Ab + (wm * 32 + 16 + lr) * 128 + koff);
      short8 bf[4];
      #pragma unroll
      for (int nf = 0; nf < 4; ++nf)
        bf[nf] = *(const short8*)(Bb + (wn * 64 + nf * 16 + lr) * 128 + koff);
      #pragma unroll
      for (int nf = 0; nf < 4; ++nf) {
        acc[0][nf] = __builtin_amdgcn_mfma_f32_16x16x32_bf16(af0, bf[nf], acc[0][nf], 0, 0, 0);
        acc[1][nf] = __builtin_amdgcn_mfma_f32_16x16x32_bf16(af1, bf[nf], acc[1][nf], 0, 0, 0);
      }
    }
    __syncthreads();
  }

  float* pp = part + (size_t)blockIdx.y * nrpad * 128 + (size_t)row0 * 128;
  #pragma unroll
  for (int mf = 0; mf < 2; ++mf)
    #pragma unroll
    for (int nf = 0; nf < 4; ++nf)
      #pragma unroll
      for (int rr = 0; rr < 4; ++rr) {
        int r = wm * 32 + mf * 16 + g2 * 4 + rr;
        int c = wn * 64 + nf * 16 + lr;
        pp[r * 128 + c] = acc[mf][nf][rr];
      }
}

// ---- reduce 4 split-K partials + bias + relu -> f1o fp32 [nr][128] ----
__global__ __launch_bounds__(256) void k_red(const float* __restrict__ part,
    const float* __restrict__ bias, float* __restrict__ f1o, int nr, int nrpad) {
  int i = blockIdx.x * 256 + threadIdx.x;
  if (i >= nr * 128) return;
  size_t stride = (size_t)nrpad * 128;
  float s = part[i] + part[stride + i] + part[2 * stride + i] + part[3 * stride + i];
  f1o[i] = fmaxf(s + bias[i & 127], 0.f);
}

// ---- fc2 ----
__global__ __launch_bounds__(256) void k4_fc2(const float* __restrict__ h,
    const float* __restrict__ w, const float* __restrict__ bias,
    float* __restrict__ out, int nr) {
  int idx = blockIdx.x * 256 + threadIdx.x;
  if (idx >= nr * 10) return;
  int b = idx / 10;
  int j = idx - b * 10;
  const float4* hp = (const float4*)(h + (size_t)b * 128);
  const float4* wp = (const float4*)(w + (size_t)j * 128);
  float s = 0.f;
  #pragma unroll
  for (int q = 0; q < 32; ++q) {
    float4 hv = hp[q];
    float4 wv = wp[q];
    s = fmaf(hv.x, wv.x, s);
    s = fmaf(hv.y, wv.y, s);
    s = fmaf(hv.z, wv.z, s);
    s = fmaf(hv.w, wv.w, s);
  }
  out[idx] = s + bias[j];
}

extern "C" void kernel_launch(void* const* d_in, const int* in_sizes, int n_in,
                              void* d_out, int out_size, void* d_ws, size_t ws_size,
                              hipStream_t stream) {
  const float* x   = (const float*)d_in[0];
  const float* w1  = (const float*)d_in[1];
  const float* b1  = (const float*)d_in[2];
  const float* w2  = (const float*)d_in[3];
  const float* b2  = (const float*)d_in[4];
  const float* fw1 = (const float*)d_in[5];
  const float* fb1 = (const float*)d_in[6];
  const float* fw2 = (const float*)d_in[7];
  const float* fb2 = (const float*)d_in[8];
  float* out = (float*)d_out;

  const int B = in_sizes[0] / 784;

  unsigned short* wt2 = (unsigned short*)d_ws;                        // 36864 B
  unsigned short* fw1t = (unsigned short*)((char*)d_ws + WT2_BYTES);  // 2359296 B
  const size_t carve = WT2_BYTES + (size_t)9216 * 128 * 2;
  char* base = (char*)d_ws + carve;
  size_t avail = (ws_size > carve) ? ws_size - carve : 0;
  const size_t per_img = (size_t)POOLN * 2 + 512 + 2048;
  int Bc = (int)(avail / per_img);
  if (Bc > B) Bc = B;
  Bc &= ~63;
  if (Bc < 64) Bc = 64;

  unsigned short* pooled = (unsigned short*)base;
  float* f1o = (float*)(base + (size_t)Bc * (POOLN * 2));
  float* part = (float*)(base + (size_t)Bc * (POOLN * 2 + 512));

  k_wt2<<<(WT2_ELEMS + 255) / 256, 256, 0, stream>>>(w2, wt2);
  k_fw1t<<<128, 256, 0, stream>>>(fw1, fw1t);

  for (int i0 = 0; i0 < B; i0 += Bc) {
    int nr = (B - i0 < Bc) ? (B - i0) : Bc;
    int mtiles = (nr + 63) / 64;
    int nrpad = mtiles * 64;
    kc_fused<<<dim3(nr, 3), 256, 0, stream>>>(x + (size_t)i0 * 784, w1, b1,
                                              wt2, b2, pooled);
    k3_fc1_mfma<<<dim3(mtiles, 4), 256, 0, stream>>>(pooled, fw1t, part, nrpad);
    k_red<<<(nr * 128 + 255) / 256, 256, 0, stream>>>(part, fb1, f1o, nr, nrpad);
    k4_fc2<<<(nr * 10 + 255) / 256, 256, 0, stream>>>(f1o, fw2, fb2,
                                                      out + (size_t)i0 * 10, nr);
  }
}

// Round 12
// 155.981 us; speedup vs baseline: 2.7284x; 1.0120x over previous
//
#include <hip/hip_runtime.h>
#include <hip/hip_bf16.h>
#include <string.h>

using short8 = __attribute__((ext_vector_type(8))) short;
using f32x4  = __attribute__((ext_vector_type(4))) float;
using f32x2  = __attribute__((ext_vector_type(2))) float;

#define POOLN     9216       // 144*64 elements (bf16) per image
#define FC1N      128
#define WT2_ELEMS 18432      // 36*64*8
#define WT2_BYTES 36864
#define H1S_STRIDE 36        // shorts per position row (72 B)
#define XS_STRIDE  29        // floats per x row (odd -> conflict-free)

#define GLL16(gp, lp) __builtin_amdgcn_global_load_lds( \
    (const __attribute__((address_space(1))) void*)(gp), \
    (__attribute__((address_space(3))) void*)(lp), 16, 0, 0)

static __device__ __forceinline__ unsigned short f2bf(float f) {
  unsigned int u = __builtin_bit_cast(unsigned int, f);
  unsigned int r = (u + 0x7FFFu + ((u >> 16) & 1u)) >> 16;
  return (unsigned short)r;
}

// packed RNE pair convert -> v_cvt_pk_bf16_f32
static __device__ __forceinline__ unsigned int pkbf(float lo, float hi) {
  __hip_bfloat162 h2 = __float22bfloat162_rn(make_float2(lo, hi));
  unsigned int r;
  memcpy(&r, &h2, sizeof(r));
  return r;
}

// ---- one-off: w2 fp32 [64][32][9] -> wt2 bf16 fragment order [(tap*4+n)][lane][8]
__global__ __launch_bounds__(256) void k_wt2(const float* __restrict__ w2,
    unsigned short* __restrict__ wt2) {
  int idx = blockIdx.x * 256 + threadIdx.x;
  if (idx >= WT2_ELEMS) return;
  int j = idx & 7;
  int l = (idx >> 3) & 63;
  int tn = idx >> 9;            // 0..35
  int tap = tn >> 2, n = tn & 3;
  int oc = n * 16 + (l & 15);
  int ic = (l >> 4) * 8 + j;
  wt2[idx] = f2bf(w2[oc * 288 + ic * 9 + tap]);
}

// ---- one-off: fc1_w [128][9216 (oc*144+sp)] -> fw1t bf16 [128][9216 (sp*64+oc)] ----
__global__ __launch_bounds__(256) void k_fw1t(const float* __restrict__ w,
    unsigned short* __restrict__ wt) {
  int c = blockIdx.x;
  __shared__ float row[9216];
  int t = threadIdx.x;
  const float* src = w + (size_t)c * 9216;
  for (int i = t; i < 9216; i += 256) row[i] = src[i];
  __syncthreads();
  unsigned short* dst = wt + (size_t)c * 9216;
  for (int k = t; k < 9216; k += 256) {
    int sp = k >> 6, oc = k & 63;
    dst[k] = f2bf(row[oc * 144 + sp]);
  }
}

// ---- fused conv1+relu+conv2+relu+maxpool, row-third tiles ----
// grid (nr, 3). conv1 uses packed fp32 (v_pk_fma_f32) on channel pairs;
// conv2: wave = local pooled row, acc[3][4]=48 regs. LDS 20.1 KB, 4 blocks/CU.
__global__ __launch_bounds__(256, 4) void kc_fused(const float* __restrict__ x,
    const float* __restrict__ w1, const float* __restrict__ b1,
    const unsigned short* __restrict__ wt2, const float* __restrict__ b2,
    unsigned short* __restrict__ pooled) {
  int img = blockIdx.x;
  int tt = blockIdx.y;
  __shared__ float xs[12 * XS_STRIDE];                            // 1392 B
  __shared__ __align__(16) unsigned short h1s[260 * H1S_STRIDE];  // 18720 B
  int t = threadIdx.x;
  int wv = t >> 6, ln = t & 63;
  int r0x = tt * 8;                      // first x/h1 global row of this third

  const float* xp = x + (size_t)img * 784 + (size_t)r0x * 28;
  for (int i = t; i < 12 * 28; i += 256) {
    int r = i / 28, c = i - r * 28;
    xs[r * XS_STRIDE + c] = xp[r * 28 + c];
  }

  // conv1 weights as channel-pair f32x2 (wave-uniform -> SGPR pairs)
  int wvu = __builtin_amdgcn_readfirstlane(wv);
  f32x2 wp[4][9], bp[4];
  #pragma unroll
  for (int p = 0; p < 4; ++p) {
    int o = wvu * 8 + p * 2;
    bp[p] = (f32x2){b1[o], b1[o + 1]};
    #pragma unroll
    for (int q = 0; q < 9; ++q)
      wp[p][q] = (f32x2){w1[o * 9 + q], w1[(o + 1) * 9 + q]};
  }
  __syncthreads();

  // conv1: lane -> column, 2 halves x 5 rows each (local h1 rows 0..9)
  if (ln < 52) {
    int half = (ln >= 26);
    int xcol = ln - half * 26;          // 0..25
    int y0 = half * 5;                  // local row base
    float win[3][3];
    #pragma unroll
    for (int c = 0; c < 3; ++c) {
      win[1][c] = xs[(y0 + 0) * XS_STRIDE + xcol + c];
      win[2][c] = xs[(y0 + 1) * XS_STRIDE + xcol + c];
    }
    #pragma unroll
    for (int i = 0; i < 5; ++i) {
      #pragma unroll
      for (int c = 0; c < 3; ++c) {
        win[0][c] = win[1][c];
        win[1][c] = win[2][c];
        win[2][c] = xs[(y0 + i + 2) * XS_STRIDE + xcol + c];
      }
      f32x2 s[4] = {bp[0], bp[1], bp[2], bp[3]};
      #pragma unroll
      for (int r = 0; r < 3; ++r)
        #pragma unroll
        for (int c = 0; c < 3; ++c) {
          f32x2 wv2 = (f32x2){win[r][c], win[r][c]};
          #pragma unroll
          for (int p = 0; p < 4; ++p)
            s[p] = __builtin_elementwise_fma(wv2, wp[p][r * 3 + c], s[p]);
        }
      unsigned int packed[4];
      const f32x2 z2 = (f32x2){0.f, 0.f};
      #pragma unroll
      for (int p = 0; p < 4; ++p) {
        f32x2 sp = __builtin_elementwise_max(s[p], z2);
        packed[p] = pkbf(sp.x, sp.y);
      }
      int pos = (y0 + i) * 26 + xcol;
      unsigned short* dst = &h1s[pos * H1S_STRIDE + wv * 8];
      *(uint2*)dst = make_uint2(packed[0], packed[1]);
      *(uint2*)(dst + 4) = make_uint2(packed[2], packed[3]);
    }
  }
  __syncthreads();

  // ---- conv2 + pool: wave = local pooled row, 3 m-tiles ----
  int col = ln & 15;
  int g = (ln >> 4) & 3;

  int abase[3];
  #pragma unroll
  for (int i = 0; i < 3; ++i) {
    int y = 2 * wv + (col & 1);                    // local h1 row
    int xx = 8 * i + (col >> 1);
    abase[i] = (y * 26 + xx) * (H1S_STRIDE * 2) + g * 16;
  }

  f32x4 acc[3][4];
  #pragma unroll
  for (int m = 0; m < 3; ++m)
    #pragma unroll
    for (int n = 0; n < 4; ++n)
      acc[m][n] = (f32x4){0.f, 0.f, 0.f, 0.f};

  const char* hsb = (const char*)h1s;
  #pragma unroll
  for (int tap = 0; tap < 9; ++tap) {
    int ky = tap / 3, kx = tap - ky * 3;
    int toff = (ky * 26 + kx) * (H1S_STRIDE * 2);
    short8 bf[4];
    #pragma unroll
    for (int n = 0; n < 4; ++n)
      bf[n] = *(const short8*)(wt2 + ((size_t)(tap * 4 + n) * 64 + ln) * 8);
    #pragma unroll
    for (int m = 0; m < 3; ++m) {
      union { short8 v; uint2 d[2]; } af;
      af.d[0] = *(const uint2*)(hsb + abase[m] + toff);
      af.d[1] = *(const uint2*)(hsb + abase[m] + toff + 8);
      #pragma unroll
      for (int n = 0; n < 4; ++n)
        acc[m][n] = __builtin_amdgcn_mfma_f32_16x16x32_bf16(af.v, bf[n], acc[m][n], 0, 0, 0);
    }
  }

  float bias[4];
  #pragma unroll
  for (int n = 0; n < 4; ++n) bias[n] = b2[n * 16 + col];
  unsigned short* pp = pooled + (size_t)img * POOLN;
  int pr = tt * 4 + wv;                            // global pooled row
  #pragma unroll
  for (int m = 0; m < 3; ++m) {
    int sp = pr * 12 + m * 4 + g;
    float rv[4];
    #pragma unroll
    for (int n = 0; n < 4; ++n) {
      f32x4 a = acc[m][n];
      float v = fmaxf(fmaxf(a[0], a[1]), fmaxf(a[2], a[3]));
      rv[n] = fmaxf(v + bias[n], 0.f);
    }
    unsigned int p01 = pkbf(rv[0], rv[1]);
    unsigned int p23 = pkbf(rv[2], rv[3]);
    unsigned short* pr0 = pp + sp * 64 + col;
    pr0[0]  = (unsigned short)p01;
    pr0[16] = (unsigned short)(p01 >> 16);
    pr0[32] = (unsigned short)p23;
    pr0[48] = (unsigned short)(p23 >> 16);
  }
}

// ---- fc1 via MFMA, split-K=4: pooled bf16 [nr][9216] @ fw1t bf16 [128][9216]^T
__global__ __launch_bounds__(256) void k3_fc1_mfma(
    const unsigned short* __restrict__ a, const unsigned short* __restrict__ w,
    float* __restrict__ part, int nrpad) {
  __shared__ __align__(16) unsigned short As[2][4096];   // [64][64] bf16 x2
  __shared__ __align__(16) unsigned short Bs[2][8192];   // [128][64] bf16 x2
  int row0 = blockIdx.x * 64;
  int kbase = blockIdx.y * 2304;
  int t = threadIdx.x;
  int wv = t >> 6, l = t & 63;
  int rsub = l >> 3;
  int src_sw = ((l & 7) ^ rsub) << 4;

  const char* abase = (const char*)a + (size_t)row0 * 18432;
  const char* bbase = (const char*)w;

  auto stage = [&](int buf, int step) {
    size_t k0b = (size_t)(kbase + step * 64) * 2;
    #pragma unroll
    for (int i = 0; i < 2; ++i) {
      int c = wv * 2 + i;
      GLL16(abase + (size_t)(c * 8 + rsub) * 18432 + k0b + src_sw,
            (char*)As[buf] + c * 1024);
    }
    #pragma unroll
    for (int i = 0; i < 4; ++i) {
      int c = wv * 4 + i;
      GLL16(bbase + (size_t)(c * 8 + rsub) * 18432 + k0b + src_sw,
            (char*)Bs[buf] + c * 1024);
    }
  };

  int wm = wv >> 1, wn = wv & 1;
  int lr = l & 15, g2 = l >> 4;
  int rdxor = (lr & 7) << 4;

  f32x4 acc[2][4];
  #pragma unroll
  for (int mf = 0; mf < 2; ++mf)
    #pragma unroll
    for (int nf = 0; nf < 4; ++nf)
      acc[mf][nf] = (f32x4){0.f, 0.f, 0.f, 0.f};

  stage(0, 0);
  __syncthreads();
  for (int s = 0; s < 36; ++s) {
    int cur = s & 1;
    if (s < 35) stage(cur ^ 1, s + 1);
    const char* Ab = (const char*)As[cur];
    const char* Bb = (const char*)Bs[cur];
    #pragma unroll
    for (int ksub = 0; ksub < 2; ++ksub) {
      int koff = (ksub * 64 + g2 * 16) ^ rdxor;
      short8 af0 = *(const short8*)(Ab + (wm * 32 + lr) * 128 + koff);
      short8 af1 = *(const short8*)(Ab + (wm * 32 + 16 + lr) * 128 + koff);
      short8 bf[4];
      #pragma unroll
      for (int nf = 0; nf < 4; ++nf)
        bf[nf] = *(const short8*)(Bb + (wn * 64 + nf * 16 + lr) * 128 + koff);
      #pragma unroll
      for (int nf = 0; nf < 4; ++nf) {
        acc[0][nf] = __builtin_amdgcn_mfma_f32_16x16x32_bf16(af0, bf[nf], acc[0][nf], 0, 0, 0);
        acc[1][nf] = __builtin_amdgcn_mfma_f32_16x16x32_bf16(af1, bf[nf], acc[1][nf], 0, 0, 0);
      }
    }
    __syncthreads();
  }

  float* pp = part + (size_t)blockIdx.y * nrpad * 128 + (size_t)row0 * 128;
  #pragma unroll
  for (int mf = 0; mf < 2; ++mf)
    #pragma unroll
    for (int nf = 0; nf < 4; ++nf)
      #pragma unroll
      for (int rr = 0; rr < 4; ++rr) {
        int r = wm * 32 + mf * 16 + g2 * 4 + rr;
        int c = wn * 64 + nf * 16 + lr;
        pp[r * 128 + c] = acc[mf][nf][rr];
      }
}

// ---- fused tail: reduce 4 split-K partials + bias + relu -> fc2 -> out ----
// block = 2 rows. Threads (t>>7, t&127) compute f1o into LDS; then 20 threads
// do the 10-wide fc2 dot from LDS (broadcast reads, conflict-free).
__global__ __launch_bounds__(256) void k_tail(const float* __restrict__ part,
    const float* __restrict__ fb1, const float* __restrict__ fw2,
    const float* __restrict__ fb2, float* __restrict__ out,
    int nr, int nrpad) {
  __shared__ float sh[2][128];
  int t = threadIdx.x;
  int r = t >> 7, c = t & 127;
  int row = blockIdx.x * 2 + r;
  size_t stride = (size_t)nrpad * 128;
  if (row < nr) {
    size_t i = (size_t)row * 128 + c;
    float s = part[i] + part[stride + i] + part[2 * stride + i] + part[3 * stride + i];
    sh[r][c] = fmaxf(s + fb1[c], 0.f);
  }
  __syncthreads();
  if (t < 20) {
    int rr = t / 10, j = t - rr * 10;
    int orow = blockIdx.x * 2 + rr;
    if (orow < nr) {
      const float4* hv = (const float4*)sh[rr];
      const float4* wv = (const float4*)(fw2 + (size_t)j * 128);
      float s = 0.f;
      #pragma unroll
      for (int q = 0; q < 32; ++q) {
        float4 h4 = hv[q];
        float4 w4 = wv[q];
        s = fmaf(h4.x, w4.x, s);
        s = fmaf(h4.y, w4.y, s);
        s = fmaf(h4.z, w4.z, s);
        s = fmaf(h4.w, w4.w, s);
      }
      out[(size_t)orow * 10 + j] = s + fb2[j];
    }
  }
}

extern "C" void kernel_launch(void* const* d_in, const int* in_sizes, int n_in,
                              void* d_out, int out_size, void* d_ws, size_t ws_size,
                              hipStream_t stream) {
  const float* x   = (const float*)d_in[0];
  const float* w1  = (const float*)d_in[1];
  const float* b1  = (const float*)d_in[2];
  const float* w2  = (const float*)d_in[3];
  const float* b2  = (const float*)d_in[4];
  const float* fw1 = (const float*)d_in[5];
  const float* fb1 = (const float*)d_in[6];
  const float* fw2 = (const float*)d_in[7];
  const float* fb2 = (const float*)d_in[8];
  float* out = (float*)d_out;

  const int B = in_sizes[0] / 784;

  unsigned short* wt2 = (unsigned short*)d_ws;                        // 36864 B
  unsigned short* fw1t = (unsigned short*)((char*)d_ws + WT2_BYTES);  // 2359296 B
  const size_t carve = WT2_BYTES + (size_t)9216 * 128 * 2;
  char* base = (char*)d_ws + carve;
  size_t avail = (ws_size > carve) ? ws_size - carve : 0;
  const size_t per_img = (size_t)POOLN * 2 + 2048;   // pooled + 4 partial rows
  int Bc = (int)(avail / per_img);
  if (Bc > B) Bc = B;
  Bc &= ~63;
  if (Bc < 64) Bc = 64;

  unsigned short* pooled = (unsigned short*)base;
  float* part = (float*)(base + (size_t)Bc * (POOLN * 2));

  k_wt2<<<(WT2_ELEMS + 255) / 256, 256, 0, stream>>>(w2, wt2);
  k_fw1t<<<128, 256, 0, stream>>>(fw1, fw1t);

  for (int i0 = 0; i0 < B; i0 += Bc) {
    int nr = (B - i0 < Bc) ? (B - i0) : Bc;
    int mtiles = (nr + 63) / 64;
    int nrpad = mtiles * 64;
    kc_fused<<<dim3(nr, 3), 256, 0, stream>>>(x + (size_t)i0 * 784, w1, b1,
                                              wt2, b2, pooled);
    k3_fc1_mfma<<<dim3(mtiles, 4), 256, 0, stream>>>(pooled, fw1t, part, nrpad);
    k_tail<<<(nr + 1) / 2, 256, 0, stream>>>(part, fb1, fw2, fb2,
                                             out + (size_t)i0 * 10, nr, nrpad);
  }
}